// Round 1
// baseline (182.173 us; speedup 1.0000x reference)
//
#include <hip/hip_runtime.h>

typedef unsigned long long u64;

#define G 512
#define T 128
#define P 256
#define B 512

struct __align__(16) U64x2 { u64 x, y; };

// Pack param_vals (B x P fp32 of 0/1) into B x 4 u64 bitmasks.
// Bit layout: word j (j=0..3), bit L  <->  p = 4*L + j. This permutation is
// applied identically to the matrices, so parity of AND is preserved.
__global__ __launch_bounds__(256) void pack_pv_kernel(
    const float* __restrict__ pv, u64* __restrict__ out)
{
    int lane = threadIdx.x & 63;
    int wave = threadIdx.x >> 6;
    int row  = blockIdx.x * 4 + wave;   // 128 blocks * 4 waves = 512 rows
    const float4* src = (const float4*)(pv + (size_t)row * P);
    float4 f = src[lane];
    u64 w0 = __ballot(f.x != 0.0f);
    u64 w1 = __ballot(f.y != 0.0f);
    u64 w2 = __ballot(f.z != 0.0f);
    u64 w3 = __ballot(f.w != 0.0f);
    if (lane == 0) {
        out[row * 4 + 0] = w0;
        out[row * 4 + 1] = w1;
        out[row * 4 + 2] = w2;
        out[row * 4 + 3] = w3;
    }
}

// One block per graph g. Phase A: pack psi/phi rows for g into LDS (8 KB).
// Phase B: each thread owns one batch b, XOR-accumulates parity over T terms.
__global__ __launch_bounds__(512) void pi_main_kernel(
    const int*   __restrict__ psi_const,
    const float* __restrict__ psi_params,
    const int*   __restrict__ phi_const,
    const float* __restrict__ phi_params,
    const u64*   __restrict__ pv,
    float4*      __restrict__ out)
{
    __shared__ __align__(16) u64 rows[T * 8];   // [t][0..3]=psi words, [4..7]=phi words
    __shared__ unsigned code_sm[T];             // bit0 = psi_const, bit1 = phi_const

    const int g    = blockIdx.x;
    const int tid  = threadIdx.x;
    const int lane = tid & 63;
    const int wave = tid >> 6;

    // Stage const bits
    if (tid < T) {
        unsigned pc = ((unsigned)psi_const[g * T + tid]) & 1u;
        unsigned qc = ((unsigned)phi_const[g * T + tid]) & 1u;
        code_sm[tid] = pc | (qc << 1);
    }

    // Stage + bit-pack matrix rows: 256 logical rows (128 psi + 128 phi), 32 per wave
    for (int i = 0; i < 32; ++i) {
        int r = wave * 32 + i;          // wave-uniform
        int t = r & (T - 1);
        const float* mat = (r < T) ? psi_params : phi_params;
        int off = (r < T) ? 0 : 4;
        const float4* src = (const float4*)(mat + ((size_t)g * T + t) * P);
        float4 f = src[lane];
        u64 w0 = __ballot(f.x != 0.0f);
        u64 w1 = __ballot(f.y != 0.0f);
        u64 w2 = __ballot(f.z != 0.0f);
        u64 w3 = __ballot(f.w != 0.0f);
        if (lane == 0) {
            U64x2* d = (U64x2*)&rows[t * 8 + off];
            U64x2 a; a.x = w0; a.y = w1;
            U64x2 c; c.x = w2; c.y = w3;
            d[0] = a;
            d[1] = c;
        }
    }
    __syncthreads();

    // Phase B: thread = batch index b
    const int b = tid;
    const u64* v = pv + (size_t)b * 4;
    u64 v0 = v[0], v1 = v[1], v2 = v[2], v3 = v[3];

    unsigned e = 0;
    #pragma unroll 8
    for (int t = 0; t < T; ++t) {
        const U64x2* row = (const U64x2*)&rows[t * 8];
        U64x2 p0 = row[0], p1 = row[1], q0 = row[2], q1 = row[3];
        // parity(x & v) over 256 bits = popcount of XOR-fold of masked words, & 1
        u64 ma = (p0.x & v0) ^ (p0.y & v1) ^ (p1.x & v2) ^ (p1.y & v3);
        u64 mb = (q0.x & v0) ^ (q0.y & v1) ^ (q1.x & v2) ^ (q1.y & v3);
        unsigned c = code_sm[t];
        // bit0 of ((popc_a ^ pc) & (popc_b ^ qc)); high bits are garbage, masked at end
        e ^= (((unsigned)__popcll(ma) ^ c) & ((unsigned)__popcll(mb) ^ (c >> 1)));
    }
    e &= 1u;

    float s = 1.0f - 2.0f * (float)e;   // (-1)^e
    out[(size_t)b * G + g] = make_float4(s, 0.0f, 0.0f, 0.0f);
}

extern "C" void kernel_launch(void* const* d_in, const int* in_sizes, int n_in,
                              void* d_out, int out_size, void* d_ws, size_t ws_size,
                              hipStream_t stream) {
    const int*   psi_const  = (const int*)  d_in[0];
    const float* psi_params = (const float*)d_in[1];
    const int*   phi_const  = (const int*)  d_in[2];
    const float* phi_params = (const float*)d_in[3];
    const float* param_vals = (const float*)d_in[4];

    u64* pv_packed = (u64*)d_ws;   // B*4 u64 = 16 KB

    pack_pv_kernel<<<B / 4, 256, 0, stream>>>(param_vals, pv_packed);
    pi_main_kernel<<<G, 512, 0, stream>>>(psi_const, psi_params,
                                          phi_const, phi_params,
                                          pv_packed, (float4*)d_out);
}